// Round 1
// baseline (787.335 us; speedup 1.0000x reference)
//
#include <hip/hip_runtime.h>

// Problem constants (fixed by the reference)
#define FDIM 128   // input features
#define HDIM 128   // hidden
#define DE   16    // edge attr dim
#define GG   32    // graphs
#define CAP  64    // max edges per node incl. self loop (deg capped at 63)
#define NEG_SLOPE 0.2f

// ---------------- degree count ----------------
__global__ void k_deg(const int* __restrict__ dst, int* __restrict__ deg, int E) {
    int i = blockIdx.x * blockDim.x + threadIdx.x;
    if (i < E) atomicAdd(&deg[dst[i]], 1);
}

// ---------------- scatter edges into padded CSR lists ----------------
__global__ void k_scatter(const int* __restrict__ src, const int* __restrict__ dst,
                          int* __restrict__ cursor, int2* __restrict__ list, int E) {
    int i = blockIdx.x * blockDim.x + threadIdx.x;
    if (i < E) {
        int d = dst[i];
        int p = atomicAdd(&cursor[d], 1);
        if (p < CAP - 1) list[d * CAP + p] = make_int2(src[i], i);
    }
}

// ---------------- fused dual GEMM: xl = x@Wl+bl, xr = x@Wr+br ----------------
// grid (ceil(M/64), 4), block 256. blockIdx.y selects 64-col slab of [Wl|Wr].
__global__ __launch_bounds__(256) void k_gemm(
    const float* __restrict__ x,
    const float* __restrict__ Wl, const float* __restrict__ bl,
    const float* __restrict__ Wr, const float* __restrict__ br,
    float* __restrict__ xl, float* __restrict__ xr, int M)
{
    __shared__ float As[32][64];   // [k][m] transposed x tile
    __shared__ float Bs[32][64];   // [k][n]
    const int c0 = blockIdx.y * 64;
    const float* __restrict__ W    = (c0 < HDIM) ? Wl : Wr;
    const float* __restrict__ bias = (c0 < HDIM) ? bl : br;
    float* __restrict__ outp       = (c0 < HDIM) ? xl : xr;
    const int cb = c0 & (HDIM - 1);
    const int r0 = blockIdx.x * 64;
    const int tid = threadIdx.x;
    const int tx = tid & 15, ty = tid >> 4;
    const int m0 = ty * 4, n0 = tx * 4;
    float acc[4][4] = {};

    for (int kc = 0; kc < FDIM; kc += 32) {
        // load x tile (transpose into As): 64 rows x 32 k, 512 float4
        #pragma unroll
        for (int vv = 0; vv < 2; ++vv) {
            int v = tid + vv * 256;
            int m = v >> 3, kq = v & 7;
            int r = r0 + m; r = (r < M) ? r : (M - 1);
            float4 xv = *reinterpret_cast<const float4*>(&x[(size_t)r * FDIM + kc + kq * 4]);
            As[kq * 4 + 0][m] = xv.x;
            As[kq * 4 + 1][m] = xv.y;
            As[kq * 4 + 2][m] = xv.z;
            As[kq * 4 + 3][m] = xv.w;
        }
        // load W tile: 32 k x 64 n
        #pragma unroll
        for (int vv = 0; vv < 2; ++vv) {
            int v = tid + vv * 256;
            int k = v >> 4, nq = v & 15;
            float4 wv = *reinterpret_cast<const float4*>(&W[(size_t)(kc + k) * HDIM + cb + nq * 4]);
            *reinterpret_cast<float4*>(&Bs[k][nq * 4]) = wv;
        }
        __syncthreads();
        #pragma unroll
        for (int k = 0; k < 32; ++k) {
            float4 a = *reinterpret_cast<const float4*>(&As[k][m0]);
            float4 b = *reinterpret_cast<const float4*>(&Bs[k][n0]);
            acc[0][0] += a.x * b.x; acc[0][1] += a.x * b.y; acc[0][2] += a.x * b.z; acc[0][3] += a.x * b.w;
            acc[1][0] += a.y * b.x; acc[1][1] += a.y * b.y; acc[1][2] += a.y * b.z; acc[1][3] += a.y * b.w;
            acc[2][0] += a.z * b.x; acc[2][1] += a.z * b.y; acc[2][2] += a.z * b.z; acc[2][3] += a.z * b.w;
            acc[3][0] += a.w * b.x; acc[3][1] += a.w * b.y; acc[3][2] += a.w * b.z; acc[3][3] += a.w * b.w;
        }
        __syncthreads();
    }
    float4 bv = *reinterpret_cast<const float4*>(&bias[cb + n0]);
    #pragma unroll
    for (int i = 0; i < 4; ++i) {
        int r = r0 + m0 + i;
        if (r < M) {
            float4 o;
            o.x = acc[i][0] + bv.x; o.y = acc[i][1] + bv.y;
            o.z = acc[i][2] + bv.z; o.w = acc[i][3] + bv.w;
            *reinterpret_cast<float4*>(&outp[(size_t)r * HDIM + cb + n0]) = o;
        }
    }
}

// ---------------- fused per-node kernel ----------------
// One block (256 thr = 4 waves) per destination node:
//  loop_attr mean, per-edge logits (1 wave/edge), segment softmax, aggregation, relu.
__global__ __launch_bounds__(256) void k_node(
    const float* __restrict__ xl, const float* __restrict__ xr,
    const float* __restrict__ edge_attr, const float* __restrict__ We,
    const float* __restrict__ att, const float* __restrict__ bias_conv,
    const int* __restrict__ deg, const int2* __restrict__ list,
    float* __restrict__ hN, int N)
{
    __shared__ float We_s[DE][HDIM];     // 8 KB
    __shared__ float ea_s[CAP][DE];      // 4 KB
    __shared__ float xlc[CAP][HDIM];     // 32 KB (xl rows cached for pass 2)
    __shared__ int   srcs[CAP];
    __shared__ float logit_s[CAP];
    __shared__ float alpha_s[CAP];
    __shared__ float la_sum[DE];
    __shared__ float out_acc[4][HDIM];   // 2 KB

    const int n   = blockIdx.x;
    const int tid = threadIdx.x;
    const int lane = tid & 63;
    const int w    = tid >> 6;

    // stage We
    for (int i = tid; i < DE * HDIM; i += 256)
        We_s[i >> 7][i & (HDIM - 1)] = We[i];
    if (tid < DE) la_sum[tid] = 0.f;
    const int dfull = deg[n];
    const int dcap  = dfull < (CAP - 1) ? dfull : (CAP - 1);
    __syncthreads();

    // phase 0: stage edge_attr rows + accumulate loop_attr sum + grab src ids
    {
        const int k = tid & (DE - 1), j0 = tid >> 4;
        float part = 0.f;
        for (int j = j0; j < dcap; j += 16) {
            int2 se = list[(size_t)n * CAP + j];
            float v = edge_attr[(size_t)se.y * DE + k];
            ea_s[j][k] = v;
            part += v;
            if (k == 0) srcs[j] = se.x;
        }
        atomicAdd(&la_sum[k], part);
    }
    __syncthreads();
    // self-loop row = mean of incoming edge_attr
    if (tid < DE) ea_s[dcap][tid] = la_sum[tid] / (float)(dfull > 1 ? dfull : 1);
    if (tid == 0) srcs[dcap] = n;
    __syncthreads();

    const int cnt = dcap + 1;
    const float xr0 = xr[(size_t)n * HDIM + lane];
    const float xr1 = xr[(size_t)n * HDIM + 64 + lane];
    const float at0 = att[lane];
    const float at1 = att[64 + lane];

    // phase 1: one wave per edge — logit
    for (int j = w; j < cnt; j += 4) {
        int s = srcs[j];
        float a0 = xl[(size_t)s * HDIM + lane];
        float a1 = xl[(size_t)s * HDIM + 64 + lane];
        xlc[j][lane]      = a0;
        xlc[j][64 + lane] = a1;
        float e0 = 0.f, e1 = 0.f;
        #pragma unroll
        for (int k = 0; k < DE; ++k) {
            float ea = ea_s[j][k];
            e0 += ea * We_s[k][lane];
            e1 += ea * We_s[k][64 + lane];
        }
        float m0 = a0 + xr0 + e0;
        float m1 = a1 + xr1 + e1;
        m0 = m0 > 0.f ? m0 : NEG_SLOPE * m0;
        m1 = m1 > 0.f ? m1 : NEG_SLOPE * m1;
        float t = m0 * at0 + m1 * at1;
        #pragma unroll
        for (int off = 32; off; off >>= 1) t += __shfl_xor(t, off);
        if (lane == 0) logit_s[j] = t;
    }
    __syncthreads();

    // phase 2: segment softmax (wave 0; cnt <= 64)
    if (w == 0) {
        float v0 = (lane < cnt) ? logit_s[lane] : -1e30f;
        float mx = v0;
        #pragma unroll
        for (int off = 32; off; off >>= 1) mx = fmaxf(mx, __shfl_xor(mx, off));
        float ex = (lane < cnt) ? __expf(v0 - mx) : 0.f;
        float den = ex;
        #pragma unroll
        for (int off = 32; off; off >>= 1) den += __shfl_xor(den, off);
        float inv = 1.f / den;
        if (lane < cnt) alpha_s[lane] = ex * inv;
    }
    __syncthreads();

    // phase 3: out[n] = sum alpha_j * xl[src_j]
    float o0 = 0.f, o1 = 0.f;
    for (int j = w; j < cnt; j += 4) {
        float a = alpha_s[j];
        o0 += a * xlc[j][lane];
        o1 += a * xlc[j][64 + lane];
    }
    out_acc[w][lane]      = o0;
    out_acc[w][64 + lane] = o1;
    __syncthreads();
    if (tid < HDIM) {
        float s = out_acc[0][tid] + out_acc[1][tid] + out_acc[2][tid] + out_acc[3][tid]
                + bias_conv[tid];
        hN[(size_t)n * HDIM + tid] = fmaxf(s, 0.f);
    }
}

// ---------------- pooled sums per graph (batch is sorted) ----------------
__global__ __launch_bounds__(128) void k_pool(
    const float* __restrict__ hN, const int* __restrict__ batch,
    float* __restrict__ pool, int* __restrict__ cnt, int N)
{
    const int t  = threadIdx.x;          // dim
    const int n0 = blockIdx.x * 256;
    if (n0 >= N) return;
    const int n1 = (n0 + 256 < N) ? (n0 + 256) : N;
    int curg = batch[n0];
    float acc = 0.f;
    int c = 0;
    for (int nn = n0; nn < n1; ++nn) {
        int g = batch[nn];
        if (g != curg) {
            atomicAdd(&pool[curg * HDIM + t], acc);
            if (t == 0) atomicAdd(&cnt[curg], c);
            acc = 0.f; c = 0; curg = g;
        }
        acc += hN[(size_t)nn * HDIM + t];
        ++c;
    }
    atomicAdd(&pool[curg * HDIM + t], acc);
    if (t == 0) atomicAdd(&cnt[curg], c);
}

// ---------------- final classifier ----------------
__global__ void k_final(const float* __restrict__ pool, const int* __restrict__ cnt,
                        const float* __restrict__ Wc, const float* __restrict__ bc,
                        float* __restrict__ out)
{
    int t = threadIdx.x;
    if (t < GG * 2) {
        int g = t >> 1, c = t & 1;
        float inv = 1.f / (float)(cnt[g] > 1 ? cnt[g] : 1);
        float s = 0.f;
        #pragma unroll 16
        for (int h = 0; h < HDIM; ++h) s += pool[g * HDIM + h] * Wc[h * 2 + c];
        out[t] = s * inv + bc[c];
    }
}

extern "C" void kernel_launch(void* const* d_in, const int* in_sizes, int n_in,
                              void* d_out, int out_size, void* d_ws, size_t ws_size,
                              hipStream_t stream) {
    const float* x         = (const float*)d_in[0];
    const int*   ei        = (const int*)  d_in[1];
    const float* edge_attr = (const float*)d_in[2];
    const int*   batch     = (const int*)  d_in[3];
    const float* Wl        = (const float*)d_in[4];
    const float* bl        = (const float*)d_in[5];
    const float* Wr        = (const float*)d_in[6];
    const float* br        = (const float*)d_in[7];
    const float* We        = (const float*)d_in[8];
    const float* att       = (const float*)d_in[9];
    const float* bias_conv = (const float*)d_in[10];
    const float* Wc        = (const float*)d_in[11];
    const float* bc        = (const float*)d_in[12];
    float* out = (float*)d_out;

    const int N = in_sizes[0] / FDIM;
    const int E = in_sizes[1] / 2;
    const int* srcp = ei;
    const int* dstp = ei + E;

    // workspace carve-up (256B aligned)
    char* ws = (char*)d_ws;
    size_t off = 0;
    auto alloc = [&](size_t bytes) { char* p = ws + off; off = (off + bytes + 255) & ~(size_t)255; return p; };
    int*   deg    = (int*)  alloc((size_t)N * 4);
    int*   cursor = (int*)  alloc((size_t)N * 4);
    int2*  list   = (int2*) alloc((size_t)N * CAP * 8);
    float* xl     = (float*)alloc((size_t)N * HDIM * 4);
    float* xr     = (float*)alloc((size_t)N * HDIM * 4);
    float* hN     = (float*)alloc((size_t)N * HDIM * 4);
    float* pool   = (float*)alloc((size_t)GG * HDIM * 4);
    int*   cnt    = (int*)  alloc((size_t)GG * 4);

    hipMemsetAsync(deg,    0, (size_t)N * 4, stream);
    hipMemsetAsync(cursor, 0, (size_t)N * 4, stream);
    hipMemsetAsync(pool,   0, (size_t)GG * HDIM * 4, stream);
    hipMemsetAsync(cnt,    0, (size_t)GG * 4, stream);

    k_deg    <<<(E + 255) / 256, 256, 0, stream>>>(dstp, deg, E);
    k_scatter<<<(E + 255) / 256, 256, 0, stream>>>(srcp, dstp, cursor, list, E);
    k_gemm   <<<dim3((N + 63) / 64, 4), 256, 0, stream>>>(x, Wl, bl, Wr, br, xl, xr, N);
    k_node   <<<N, 256, 0, stream>>>(xl, xr, edge_attr, We, att, bias_conv, deg, list, hN, N);
    k_pool   <<<(N + 255) / 256, 128, 0, stream>>>(hN, batch, pool, cnt, N);
    k_final  <<<1, 64, 0, stream>>>(pool, cnt, Wc, bc, out);
}

// Round 2
// 771.150 us; speedup vs baseline: 1.0210x; 1.0210x over previous
//
#include <hip/hip_runtime.h>

// Problem constants (fixed by the reference)
#define FDIM 128   // input features
#define HDIM 128   // hidden
#define DE   16    // edge attr dim
#define GG   32    // graphs
#define CAP  64    // max edges per node incl. self loop (deg capped at 63)
#define NPB  4     // nodes per block (one wave per node)
#define NEG_SLOPE 0.2f

// ---------------- scatter edges into padded CSR lists (cursor == degree) ----------------
__global__ void k_scatter(const int* __restrict__ src, const int* __restrict__ dst,
                          int* __restrict__ cursor, int2* __restrict__ list, int E) {
    int i = blockIdx.x * blockDim.x + threadIdx.x;
    if (i < E) {
        int d = dst[i];
        int p = atomicAdd(&cursor[d], 1);
        if (p < CAP - 1) list[d * CAP + p] = make_int2(src[i], i);
    }
}

// ---------------- fused dual GEMM: xl = x@Wl+bl, xr = x@Wr+br ----------------
// grid (ceil(M/64), 4), block 256. blockIdx.y selects 64-col slab of [Wl|Wr].
__global__ __launch_bounds__(256) void k_gemm(
    const float* __restrict__ x,
    const float* __restrict__ Wl, const float* __restrict__ bl,
    const float* __restrict__ Wr, const float* __restrict__ br,
    float* __restrict__ xl, float* __restrict__ xr, int M)
{
    __shared__ float As[32][64];   // [k][m] transposed x tile
    __shared__ float Bs[32][64];   // [k][n]
    const int c0 = blockIdx.y * 64;
    const float* __restrict__ W    = (c0 < HDIM) ? Wl : Wr;
    const float* __restrict__ bias = (c0 < HDIM) ? bl : br;
    float* __restrict__ outp       = (c0 < HDIM) ? xl : xr;
    const int cb = c0 & (HDIM - 1);
    const int r0 = blockIdx.x * 64;
    const int tid = threadIdx.x;
    const int tx = tid & 15, ty = tid >> 4;
    const int m0 = ty * 4, n0 = tx * 4;
    float acc[4][4] = {};

    for (int kc = 0; kc < FDIM; kc += 32) {
        #pragma unroll
        for (int vv = 0; vv < 2; ++vv) {
            int v = tid + vv * 256;
            int m = v >> 3, kq = v & 7;
            int r = r0 + m; r = (r < M) ? r : (M - 1);
            float4 xv = *reinterpret_cast<const float4*>(&x[(size_t)r * FDIM + kc + kq * 4]);
            As[kq * 4 + 0][m] = xv.x;
            As[kq * 4 + 1][m] = xv.y;
            As[kq * 4 + 2][m] = xv.z;
            As[kq * 4 + 3][m] = xv.w;
        }
        #pragma unroll
        for (int vv = 0; vv < 2; ++vv) {
            int v = tid + vv * 256;
            int k = v >> 4, nq = v & 15;
            float4 wv = *reinterpret_cast<const float4*>(&W[(size_t)(kc + k) * HDIM + cb + nq * 4]);
            *reinterpret_cast<float4*>(&Bs[k][nq * 4]) = wv;
        }
        __syncthreads();
        #pragma unroll
        for (int k = 0; k < 32; ++k) {
            float4 a = *reinterpret_cast<const float4*>(&As[k][m0]);
            float4 b = *reinterpret_cast<const float4*>(&Bs[k][n0]);
            acc[0][0] += a.x * b.x; acc[0][1] += a.x * b.y; acc[0][2] += a.x * b.z; acc[0][3] += a.x * b.w;
            acc[1][0] += a.y * b.x; acc[1][1] += a.y * b.y; acc[1][2] += a.y * b.z; acc[1][3] += a.y * b.w;
            acc[2][0] += a.z * b.x; acc[2][1] += a.z * b.y; acc[2][2] += a.z * b.z; acc[2][3] += a.z * b.w;
            acc[3][0] += a.w * b.x; acc[3][1] += a.w * b.y; acc[3][2] += a.w * b.z; acc[3][3] += a.w * b.w;
        }
        __syncthreads();
    }
    float4 bv = *reinterpret_cast<const float4*>(&bias[cb + n0]);
    #pragma unroll
    for (int i = 0; i < 4; ++i) {
        int r = r0 + m0 + i;
        if (r < M) {
            float4 o;
            o.x = acc[i][0] + bv.x; o.y = acc[i][1] + bv.y;
            o.z = acc[i][2] + bv.z; o.w = acc[i][3] + bv.w;
            *reinterpret_cast<float4*>(&outp[(size_t)r * HDIM + cb + n0]) = o;
        }
    }
}

// ---------------- fused per-node kernel: ONE WAVE PER NODE ----------------
// 256 thr = 4 waves = 4 nodes/block. Only LDS: We (8 KB). No per-node barriers.
// Lane j holds edge j's (src, edge_attr). Everything else via shuffles.
__global__ __launch_bounds__(256, 8) void k_node(
    const float* __restrict__ xl, const float* __restrict__ xr,
    const float* __restrict__ edge_attr, const float* __restrict__ We,
    const float* __restrict__ att, const float* __restrict__ bias_conv,
    const int* __restrict__ deg, const int2* __restrict__ list,
    float* __restrict__ hN, int N)
{
    __shared__ float We_s[DE][HDIM];     // 8 KB

    const int tid  = threadIdx.x;
    const int lane = tid & 63;
    const int w    = tid >> 6;
    const int n    = blockIdx.x * NPB + w;

    // stage We (512 float4 / 256 threads)
    {
        const float4* W4 = reinterpret_cast<const float4*>(We);
        float4* S4 = reinterpret_cast<float4*>(&We_s[0][0]);
        S4[tid]       = W4[tid];
        S4[tid + 256] = W4[tid + 256];
    }
    __syncthreads();
    if (n >= N) return;

    const int dfull = deg[n];
    const int dcap  = dfull < (CAP - 1) ? dfull : (CAP - 1);
    const int cnt   = dcap + 1;

    // lane j <- edge j (src id + 16 attrs); lane dcap = self loop
    int   src_reg = n;
    float ea[DE];
    #pragma unroll
    for (int k = 0; k < DE; ++k) ea[k] = 0.f;
    if (lane < dcap) {
        int2 se = list[(size_t)n * CAP + lane];
        src_reg = se.x;
        const float4* ep = reinterpret_cast<const float4*>(&edge_attr[(size_t)se.y * DE]);
        float4 v0 = ep[0], v1 = ep[1], v2 = ep[2], v3 = ep[3];
        ea[0]=v0.x; ea[1]=v0.y; ea[2]=v0.z; ea[3]=v0.w;
        ea[4]=v1.x; ea[5]=v1.y; ea[6]=v1.z; ea[7]=v1.w;
        ea[8]=v2.x; ea[9]=v2.y; ea[10]=v2.z; ea[11]=v2.w;
        ea[12]=v3.x; ea[13]=v3.y; ea[14]=v3.z; ea[15]=v3.w;
    }
    // self-loop attr = mean of incoming edge_attr (lanes >= dcap contribute 0)
    {
        const float invd = 1.f / (float)(dfull > 1 ? dfull : 1);
        #pragma unroll
        for (int k = 0; k < DE; ++k) {
            float v = ea[k];
            #pragma unroll
            for (int off = 32; off; off >>= 1) v += __shfl_xor(v, off);
            if (lane == dcap) ea[k] = v * invd;
        }
    }

    const float xr0 = xr[(size_t)n * HDIM + lane];
    const float xr1 = xr[(size_t)n * HDIM + 64 + lane];
    const float at0 = att[lane];
    const float at1 = att[64 + lane];

    // pass 1: logit per edge (wave-cooperative over 128 dims)
    float mylogit = 0.f;
    for (int j = 0; j < cnt; ++j) {
        int s = __shfl(src_reg, j);
        float a0 = xl[(size_t)s * HDIM + lane];
        float a1 = xl[(size_t)s * HDIM + 64 + lane];
        float e0 = 0.f, e1 = 0.f;
        #pragma unroll
        for (int k = 0; k < DE; ++k) {
            float ek = __shfl(ea[k], j);
            e0 = fmaf(ek, We_s[k][lane], e0);
            e1 = fmaf(ek, We_s[k][64 + lane], e1);
        }
        float m0 = a0 + xr0 + e0;
        float m1 = a1 + xr1 + e1;
        m0 = m0 > 0.f ? m0 : NEG_SLOPE * m0;
        m1 = m1 > 0.f ? m1 : NEG_SLOPE * m1;
        float t = fmaf(m0, at0, m1 * at1);
        #pragma unroll
        for (int off = 32; off; off >>= 1) t += __shfl_xor(t, off);
        if (lane == j) mylogit = t;
    }

    // in-wave segment softmax (cnt <= 64, one logit per lane)
    float v = (lane < cnt) ? mylogit : -1e30f;
    float mx = v;
    #pragma unroll
    for (int off = 32; off; off >>= 1) mx = fmaxf(mx, __shfl_xor(mx, off));
    float ex = (lane < cnt) ? __expf(v - mx) : 0.f;
    float den = ex;
    #pragma unroll
    for (int off = 32; off; off >>= 1) den += __shfl_xor(den, off);
    const float alpha = ex / den;

    // pass 2: out[n] = sum_j alpha_j * xl[src_j]  (rows are L1/L2-hot)
    float o0 = 0.f, o1 = 0.f;
    for (int j = 0; j < cnt; ++j) {
        float a = __shfl(alpha, j);
        int   s = __shfl(src_reg, j);
        o0 = fmaf(a, xl[(size_t)s * HDIM + lane], o0);
        o1 = fmaf(a, xl[(size_t)s * HDIM + 64 + lane], o1);
    }
    o0 = fmaxf(o0 + bias_conv[lane], 0.f);
    o1 = fmaxf(o1 + bias_conv[64 + lane], 0.f);
    hN[(size_t)n * HDIM + lane]      = o0;
    hN[(size_t)n * HDIM + 64 + lane] = o1;
}

// ---------------- pooled sums per graph (batch is sorted) ----------------
__global__ __launch_bounds__(128) void k_pool(
    const float* __restrict__ hN, const int* __restrict__ batch,
    float* __restrict__ pool, int* __restrict__ cnt, int N)
{
    const int t  = threadIdx.x;          // dim
    const int n0 = blockIdx.x * 256;
    if (n0 >= N) return;
    const int n1 = (n0 + 256 < N) ? (n0 + 256) : N;
    int curg = batch[n0];
    float acc = 0.f;
    int c = 0;
    for (int nn = n0; nn < n1; ++nn) {
        int g = batch[nn];
        if (g != curg) {
            atomicAdd(&pool[curg * HDIM + t], acc);
            if (t == 0) atomicAdd(&cnt[curg], c);
            acc = 0.f; c = 0; curg = g;
        }
        acc += hN[(size_t)nn * HDIM + t];
        ++c;
    }
    atomicAdd(&pool[curg * HDIM + t], acc);
    if (t == 0) atomicAdd(&cnt[curg], c);
}

// ---------------- final classifier ----------------
__global__ void k_final(const float* __restrict__ pool, const int* __restrict__ cnt,
                        const float* __restrict__ Wc, const float* __restrict__ bc,
                        float* __restrict__ out)
{
    int t = threadIdx.x;
    if (t < GG * 2) {
        int g = t >> 1, c = t & 1;
        float inv = 1.f / (float)(cnt[g] > 1 ? cnt[g] : 1);
        float s = 0.f;
        #pragma unroll 16
        for (int h = 0; h < HDIM; ++h) s += pool[g * HDIM + h] * Wc[h * 2 + c];
        out[t] = s * inv + bc[c];
    }
}

extern "C" void kernel_launch(void* const* d_in, const int* in_sizes, int n_in,
                              void* d_out, int out_size, void* d_ws, size_t ws_size,
                              hipStream_t stream) {
    const float* x         = (const float*)d_in[0];
    const int*   ei        = (const int*)  d_in[1];
    const float* edge_attr = (const float*)d_in[2];
    const int*   batch     = (const int*)  d_in[3];
    const float* Wl        = (const float*)d_in[4];
    const float* bl        = (const float*)d_in[5];
    const float* Wr        = (const float*)d_in[6];
    const float* br        = (const float*)d_in[7];
    const float* We        = (const float*)d_in[8];
    const float* att       = (const float*)d_in[9];
    const float* bias_conv = (const float*)d_in[10];
    const float* Wc        = (const float*)d_in[11];
    const float* bc        = (const float*)d_in[12];
    float* out = (float*)d_out;

    const int N = in_sizes[0] / FDIM;
    const int E = in_sizes[1] / 2;
    const int* srcp = ei;
    const int* dstp = ei + E;

    // workspace carve-up (256B aligned)
    char* ws = (char*)d_ws;
    size_t off = 0;
    auto alloc = [&](size_t bytes) { char* p = ws + off; off = (off + bytes + 255) & ~(size_t)255; return p; };
    int*   cursor = (int*)  alloc((size_t)N * 4);          // doubles as degree
    int2*  list   = (int2*) alloc((size_t)N * CAP * 8);
    float* xl     = (float*)alloc((size_t)N * HDIM * 4);
    float* xr     = (float*)alloc((size_t)N * HDIM * 4);
    float* hN     = (float*)alloc((size_t)N * HDIM * 4);
    float* pool   = (float*)alloc((size_t)GG * HDIM * 4);
    int*   cnt    = (int*)  alloc((size_t)GG * 4);

    hipMemsetAsync(cursor, 0, (size_t)N * 4, stream);
    hipMemsetAsync(pool,   0, (size_t)GG * HDIM * 4, stream);
    hipMemsetAsync(cnt,    0, (size_t)GG * 4, stream);

    k_scatter<<<(E + 255) / 256, 256, 0, stream>>>(srcp, dstp, cursor, list, E);
    k_gemm   <<<dim3((N + 63) / 64, 4), 256, 0, stream>>>(x, Wl, bl, Wr, br, xl, xr, N);
    k_node   <<<(N + NPB - 1) / NPB, 256, 0, stream>>>(xl, xr, edge_attr, We, att, bias_conv,
                                                       cursor, list, hN, N);
    k_pool   <<<(N + 255) / 256, 128, 0, stream>>>(hN, batch, pool, cnt, N);
    k_final  <<<1, 64, 0, stream>>>(pool, cnt, Wc, bc, out);
}

// Round 3
// 733.837 us; speedup vs baseline: 1.0729x; 1.0508x over previous
//
#include <hip/hip_runtime.h>

// Problem constants (fixed by the reference)
#define FDIM 128   // input features
#define HDIM 128   // hidden
#define DE   16    // edge attr dim
#define GG   32    // graphs
#define CAP  64    // max edges per node incl. self loop (deg capped at 63)
#define NPB  4     // nodes per block (one wave per node)
#define NEG_SLOPE 0.2f

// ---------------- scatter edges into padded CSR lists (cursor == degree) ----------------
__global__ void k_scatter(const int* __restrict__ src, const int* __restrict__ dst,
                          int* __restrict__ cursor, int2* __restrict__ list, int E) {
    int i = blockIdx.x * blockDim.x + threadIdx.x;
    if (i < E) {
        int d = dst[i];
        int p = atomicAdd(&cursor[d], 1);
        if (p < CAP - 1) list[d * CAP + p] = make_int2(src[i], i);
    }
}

// ---------------- fused dual GEMM: xl = x@Wl+bl, xr = x@Wr+br ----------------
// grid (ceil(M/64), 4), block 256. blockIdx.y selects 64-col slab of [Wl|Wr].
__global__ __launch_bounds__(256) void k_gemm(
    const float* __restrict__ x,
    const float* __restrict__ Wl, const float* __restrict__ bl,
    const float* __restrict__ Wr, const float* __restrict__ br,
    float* __restrict__ xl, float* __restrict__ xr, int M)
{
    __shared__ float As[32][64];   // [k][m] transposed x tile
    __shared__ float Bs[32][64];   // [k][n]
    const int c0 = blockIdx.y * 64;
    const float* __restrict__ W    = (c0 < HDIM) ? Wl : Wr;
    const float* __restrict__ bias = (c0 < HDIM) ? bl : br;
    float* __restrict__ outp       = (c0 < HDIM) ? xl : xr;
    const int cb = c0 & (HDIM - 1);
    const int r0 = blockIdx.x * 64;
    const int tid = threadIdx.x;
    const int tx = tid & 15, ty = tid >> 4;
    const int m0 = ty * 4, n0 = tx * 4;
    float acc[4][4] = {};

    for (int kc = 0; kc < FDIM; kc += 32) {
        #pragma unroll
        for (int vv = 0; vv < 2; ++vv) {
            int v = tid + vv * 256;
            int m = v >> 3, kq = v & 7;
            int r = r0 + m; r = (r < M) ? r : (M - 1);
            float4 xv = *reinterpret_cast<const float4*>(&x[(size_t)r * FDIM + kc + kq * 4]);
            As[kq * 4 + 0][m] = xv.x;
            As[kq * 4 + 1][m] = xv.y;
            As[kq * 4 + 2][m] = xv.z;
            As[kq * 4 + 3][m] = xv.w;
        }
        #pragma unroll
        for (int vv = 0; vv < 2; ++vv) {
            int v = tid + vv * 256;
            int k = v >> 4, nq = v & 15;
            float4 wv = *reinterpret_cast<const float4*>(&W[(size_t)(kc + k) * HDIM + cb + nq * 4]);
            *reinterpret_cast<float4*>(&Bs[k][nq * 4]) = wv;
        }
        __syncthreads();
        #pragma unroll
        for (int k = 0; k < 32; ++k) {
            float4 a = *reinterpret_cast<const float4*>(&As[k][m0]);
            float4 b = *reinterpret_cast<const float4*>(&Bs[k][n0]);
            acc[0][0] += a.x * b.x; acc[0][1] += a.x * b.y; acc[0][2] += a.x * b.z; acc[0][3] += a.x * b.w;
            acc[1][0] += a.y * b.x; acc[1][1] += a.y * b.y; acc[1][2] += a.y * b.z; acc[1][3] += a.y * b.w;
            acc[2][0] += a.z * b.x; acc[2][1] += a.z * b.y; acc[2][2] += a.z * b.z; acc[2][3] += a.z * b.w;
            acc[3][0] += a.w * b.x; acc[3][1] += a.w * b.y; acc[3][2] += a.w * b.z; acc[3][3] += a.w * b.w;
        }
        __syncthreads();
    }
    float4 bv = *reinterpret_cast<const float4*>(&bias[cb + n0]);
    #pragma unroll
    for (int i = 0; i < 4; ++i) {
        int r = r0 + m0 + i;
        if (r < M) {
            float4 o;
            o.x = acc[i][0] + bv.x; o.y = acc[i][1] + bv.y;
            o.z = acc[i][2] + bv.z; o.w = acc[i][3] + bv.w;
            *reinterpret_cast<float4*>(&outp[(size_t)r * HDIM + cb + n0]) = o;
        }
    }
}

// ---------------- fused per-node kernel: ONE WAVE PER NODE, ONLINE SOFTMAX ----------------
// 256 thr = 4 waves = 4 nodes/block. Single pass over edges: each xl row gather feeds
// BOTH the logit and the (flash-style rescaled) aggregation. Lane j holds edge j's
// (src, edge_attr); lane l handles output dims (2l, 2l+1) as float2.
__global__ __launch_bounds__(256, 8) void k_node(
    const float* __restrict__ xl, const float* __restrict__ xr,
    const float* __restrict__ edge_attr, const float* __restrict__ We,
    const float* __restrict__ att, const float* __restrict__ bias_conv,
    const int* __restrict__ deg, const int2* __restrict__ list,
    float* __restrict__ hN, int N)
{
    __shared__ float We_s[DE][HDIM];     // 8 KB

    const int tid  = threadIdx.x;
    const int lane = tid & 63;
    const int w    = tid >> 6;
    const int n    = blockIdx.x * NPB + w;

    // stage We (512 float4 / 256 threads)
    {
        const float4* W4 = reinterpret_cast<const float4*>(We);
        float4* S4 = reinterpret_cast<float4*>(&We_s[0][0]);
        S4[tid]       = W4[tid];
        S4[tid + 256] = W4[tid + 256];
    }
    __syncthreads();
    if (n >= N) return;

    const int dfull = deg[n];
    const int dcap  = dfull < (CAP - 1) ? dfull : (CAP - 1);
    const int cnt   = dcap + 1;

    // lane j <- edge j (src id + 16 attrs); lane dcap = self loop
    int   src_reg = n;
    float ea[DE];
    #pragma unroll
    for (int k = 0; k < DE; ++k) ea[k] = 0.f;
    if (lane < dcap) {
        int2 se = list[(size_t)n * CAP + lane];
        src_reg = se.x;
        const float4* ep = reinterpret_cast<const float4*>(&edge_attr[(size_t)se.y * DE]);
        float4 v0 = ep[0], v1 = ep[1], v2 = ep[2], v3 = ep[3];
        ea[0]=v0.x; ea[1]=v0.y; ea[2]=v0.z; ea[3]=v0.w;
        ea[4]=v1.x; ea[5]=v1.y; ea[6]=v1.z; ea[7]=v1.w;
        ea[8]=v2.x; ea[9]=v2.y; ea[10]=v2.z; ea[11]=v2.w;
        ea[12]=v3.x; ea[13]=v3.y; ea[14]=v3.z; ea[15]=v3.w;
    }
    // self-loop attr = mean of incoming edge_attr (lanes >= dcap contribute 0)
    {
        const float invd = 1.f / (float)(dfull > 1 ? dfull : 1);
        #pragma unroll
        for (int k = 0; k < DE; ++k) {
            float v = ea[k];
            #pragma unroll
            for (int off = 32; off; off >>= 1) v += __shfl_xor(v, off);
            if (lane == dcap) ea[k] = v * invd;
        }
    }

    // per-lane dims: d0 = 2*lane, d1 = 2*lane+1 (one float2 covers the 512B row per wave)
    const float2 xr2 = *reinterpret_cast<const float2*>(&xr[(size_t)n * HDIM + 2 * lane]);
    const float2 at2 = *reinterpret_cast<const float2*>(&att[2 * lane]);

    // online softmax state
    float m = -1e30f, d = 0.f, o0 = 0.f, o1 = 0.f;

    // prefetch edge 0's xl row
    int   s_pf = __shfl(src_reg, 0);
    float2 a_pf = *reinterpret_cast<const float2*>(&xl[(size_t)s_pf * HDIM + 2 * lane]);

    for (int j = 0; j < cnt; ++j) {
        const float a0 = a_pf.x, a1 = a_pf.y;
        // prefetch next edge's row (clamped lane index keeps it in-bounds)
        int jn = j + 1 < cnt ? j + 1 : cnt - 1;
        int sn = __shfl(src_reg, jn);
        a_pf = *reinterpret_cast<const float2*>(&xl[(size_t)sn * HDIM + 2 * lane]);

        // e = ea_j @ We  (ea_j broadcast from lane j)
        float e0 = 0.f, e1 = 0.f;
        #pragma unroll
        for (int k = 0; k < DE; ++k) {
            float ek = __shfl(ea[k], j);
            e0 = fmaf(ek, We_s[k][2 * lane],     e0);
            e1 = fmaf(ek, We_s[k][2 * lane + 1], e1);
        }
        float m0 = a0 + xr2.x + e0;
        float m1 = a1 + xr2.y + e1;
        m0 = m0 > 0.f ? m0 : NEG_SLOPE * m0;
        m1 = m1 > 0.f ? m1 : NEG_SLOPE * m1;
        float t = fmaf(m0, at2.x, m1 * at2.y);
        #pragma unroll
        for (int off = 32; off; off >>= 1) t += __shfl_xor(t, off);   // all lanes get logit

        // online-softmax update (wave-uniform m,d; per-lane o)
        float mnew = fmaxf(m, t);
        float sc   = __expf(m - mnew);     // 0 on first iter (m=-1e30)
        float p    = __expf(t - mnew);
        d  = d * sc + p;
        o0 = o0 * sc + p * a0;
        o1 = o1 * sc + p * a1;
        m  = mnew;
    }

    const float inv = 1.f / d;
    const float2 bc2 = *reinterpret_cast<const float2*>(&bias_conv[2 * lane]);
    float2 res;
    res.x = fmaxf(fmaf(o0, inv, bc2.x), 0.f);
    res.y = fmaxf(fmaf(o1, inv, bc2.y), 0.f);
    *reinterpret_cast<float2*>(&hN[(size_t)n * HDIM + 2 * lane]) = res;
}

// ---------------- pooled sums per graph (batch is sorted) ----------------
__global__ __launch_bounds__(128) void k_pool(
    const float* __restrict__ hN, const int* __restrict__ batch,
    float* __restrict__ pool, int* __restrict__ cnt, int N)
{
    const int t  = threadIdx.x;          // dim
    const int n0 = blockIdx.x * 256;
    if (n0 >= N) return;
    const int n1 = (n0 + 256 < N) ? (n0 + 256) : N;
    int curg = batch[n0];
    float acc = 0.f;
    int c = 0;
    for (int nn = n0; nn < n1; ++nn) {
        int g = batch[nn];
        if (g != curg) {
            atomicAdd(&pool[curg * HDIM + t], acc);
            if (t == 0) atomicAdd(&cnt[curg], c);
            acc = 0.f; c = 0; curg = g;
        }
        acc += hN[(size_t)nn * HDIM + t];
        ++c;
    }
    atomicAdd(&pool[curg * HDIM + t], acc);
    if (t == 0) atomicAdd(&cnt[curg], c);
}

// ---------------- final classifier ----------------
__global__ void k_final(const float* __restrict__ pool, const int* __restrict__ cnt,
                        const float* __restrict__ Wc, const float* __restrict__ bc,
                        float* __restrict__ out)
{
    int t = threadIdx.x;
    if (t < GG * 2) {
        int g = t >> 1, c = t & 1;
        float inv = 1.f / (float)(cnt[g] > 1 ? cnt[g] : 1);
        float s = 0.f;
        #pragma unroll 16
        for (int h = 0; h < HDIM; ++h) s += pool[g * HDIM + h] * Wc[h * 2 + c];
        out[t] = s * inv + bc[c];
    }
}

extern "C" void kernel_launch(void* const* d_in, const int* in_sizes, int n_in,
                              void* d_out, int out_size, void* d_ws, size_t ws_size,
                              hipStream_t stream) {
    const float* x         = (const float*)d_in[0];
    const int*   ei        = (const int*)  d_in[1];
    const float* edge_attr = (const float*)d_in[2];
    const int*   batch     = (const int*)  d_in[3];
    const float* Wl        = (const float*)d_in[4];
    const float* bl        = (const float*)d_in[5];
    const float* Wr        = (const float*)d_in[6];
    const float* br        = (const float*)d_in[7];
    const float* We        = (const float*)d_in[8];
    const float* att       = (const float*)d_in[9];
    const float* bias_conv = (const float*)d_in[10];
    const float* Wc        = (const float*)d_in[11];
    const float* bc        = (const float*)d_in[12];
    float* out = (float*)d_out;

    const int N = in_sizes[0] / FDIM;
    const int E = in_sizes[1] / 2;
    const int* srcp = ei;
    const int* dstp = ei + E;

    // workspace carve-up (256B aligned)
    char* ws = (char*)d_ws;
    size_t off = 0;
    auto alloc = [&](size_t bytes) { char* p = ws + off; off = (off + bytes + 255) & ~(size_t)255; return p; };
    int*   cursor = (int*)  alloc((size_t)N * 4);          // doubles as degree
    int2*  list   = (int2*) alloc((size_t)N * CAP * 8);
    float* xl     = (float*)alloc((size_t)N * HDIM * 4);
    float* xr     = (float*)alloc((size_t)N * HDIM * 4);
    float* hN     = (float*)alloc((size_t)N * HDIM * 4);
    float* pool   = (float*)alloc((size_t)GG * HDIM * 4);
    int*   cnt    = (int*)  alloc((size_t)GG * 4);

    hipMemsetAsync(cursor, 0, (size_t)N * 4, stream);
    hipMemsetAsync(pool,   0, (size_t)GG * HDIM * 4, stream);
    hipMemsetAsync(cnt,    0, (size_t)GG * 4, stream);

    k_scatter<<<(E + 255) / 256, 256, 0, stream>>>(srcp, dstp, cursor, list, E);
    k_gemm   <<<dim3((N + 63) / 64, 4), 256, 0, stream>>>(x, Wl, bl, Wr, br, xl, xr, N);
    k_node   <<<(N + NPB - 1) / NPB, 256, 0, stream>>>(xl, xr, edge_attr, We, att, bias_conv,
                                                       cursor, list, hN, N);
    k_pool   <<<(N + 255) / 256, 128, 0, stream>>>(hN, batch, pool, cnt, N);
    k_final  <<<1, 64, 0, stream>>>(pool, cnt, Wc, bc, out);
}

// Round 4
// 428.041 us; speedup vs baseline: 1.8394x; 1.7144x over previous
//
#include <hip/hip_runtime.h>

// Problem constants (fixed by the reference)
#define FDIM 128   // input features
#define HDIM 128   // hidden
#define DE   16    // edge attr dim
#define GG   32    // graphs
#define CAP  64    // max edges per node incl. self loop (deg capped at 63)
#define NPB  4     // nodes per block (one wave per node)
#define EA_STRIDE 20  // padded LDS row stride (floats); 80B = 5*16B, 16B-aligned rows
#define NEG_SLOPE 0.2f

// ---------------- scatter edges into padded CSR lists (cursor == degree) ----------------
__global__ void k_scatter(const int* __restrict__ src, const int* __restrict__ dst,
                          int* __restrict__ cursor, int2* __restrict__ list, int E) {
    int i = blockIdx.x * blockDim.x + threadIdx.x;
    if (i < E) {
        int d = dst[i];
        int p = atomicAdd(&cursor[d], 1);
        if (p < CAP - 1) list[d * CAP + p] = make_int2(src[i], i);
    }
}

// ---------------- fused dual GEMM: xl = x@Wl+bl, xr = x@Wr+br ----------------
// grid (ceil(M/128), 4): slab 0,1 -> Wl cols [0|64], slab 2,3 -> Wr cols [0|64].
// 256 thr; each thread: rows {ty*4..+3, 64+ty*4..+3} x cols {tx*4..+3}.
__global__ __launch_bounds__(256) void k_gemm(
    const float* __restrict__ x,
    const float* __restrict__ Wl, const float* __restrict__ bl,
    const float* __restrict__ Wr, const float* __restrict__ br,
    float* __restrict__ xl, float* __restrict__ xr, int M)
{
    __shared__ float As[32][128];   // [k][m] 16 KB
    __shared__ float Bs[32][64];    // [k][n]  8 KB
    const int slab = blockIdx.y;
    const float* __restrict__ W    = (slab < 2) ? Wl : Wr;
    const float* __restrict__ bias = (slab < 2) ? bl : br;
    float* __restrict__ outp       = (slab < 2) ? xl : xr;
    const int cb = (slab & 1) * 64;
    const int r0 = blockIdx.x * 128;
    const int tid = threadIdx.x;
    const int tx = tid & 15, ty = tid >> 4;
    const int ma = ty * 4, mb = 64 + ty * 4, n0 = tx * 4;
    float acc[8][4] = {};

    for (int kc = 0; kc < FDIM; kc += 32) {
        // As: 128 rows x 32 k -> 1024 float4, 4 per thread (transposed store)
        #pragma unroll
        for (int vv = 0; vv < 4; ++vv) {
            int v = tid + vv * 256;
            int mrow = v >> 3, kq = v & 7;
            int r = r0 + mrow; r = (r < M) ? r : (M - 1);
            float4 xv = *reinterpret_cast<const float4*>(&x[(size_t)r * FDIM + kc + kq * 4]);
            As[kq * 4 + 0][mrow] = xv.x;
            As[kq * 4 + 1][mrow] = xv.y;
            As[kq * 4 + 2][mrow] = xv.z;
            As[kq * 4 + 3][mrow] = xv.w;
        }
        // Bs: 32 k x 64 n -> 512 float4, 2 per thread
        #pragma unroll
        for (int vv = 0; vv < 2; ++vv) {
            int v = tid + vv * 256;
            int k = v >> 4, nq = v & 15;
            *reinterpret_cast<float4*>(&Bs[k][nq * 4]) =
                *reinterpret_cast<const float4*>(&W[(size_t)(kc + k) * HDIM + cb + nq * 4]);
        }
        __syncthreads();
        #pragma unroll
        for (int k = 0; k < 32; ++k) {
            float4 b4 = *reinterpret_cast<const float4*>(&Bs[k][n0]);
            float4 aa = *reinterpret_cast<const float4*>(&As[k][ma]);
            float4 ab = *reinterpret_cast<const float4*>(&As[k][mb]);
            float a8[8] = {aa.x, aa.y, aa.z, aa.w, ab.x, ab.y, ab.z, ab.w};
            #pragma unroll
            for (int i = 0; i < 8; ++i) {
                acc[i][0] = fmaf(a8[i], b4.x, acc[i][0]);
                acc[i][1] = fmaf(a8[i], b4.y, acc[i][1]);
                acc[i][2] = fmaf(a8[i], b4.z, acc[i][2]);
                acc[i][3] = fmaf(a8[i], b4.w, acc[i][3]);
            }
        }
        __syncthreads();
    }
    float4 bv = *reinterpret_cast<const float4*>(&bias[cb + n0]);
    #pragma unroll
    for (int i = 0; i < 8; ++i) {
        int r = r0 + ((i < 4) ? (ma + i) : (mb + i - 4));
        if (r < M) {
            float4 o;
            o.x = acc[i][0] + bv.x; o.y = acc[i][1] + bv.y;
            o.z = acc[i][2] + bv.z; o.w = acc[i][3] + bv.w;
            *reinterpret_cast<float4*>(&outp[(size_t)r * HDIM + cb + n0]) = o;
        }
    }
}

// ---------------- fused per-node kernel: ONE WAVE PER NODE, 8-EDGE BATCHES ----------------
// Lane l owns output dims (2l, 2l+1). We columns cached in 32 VGPRs. ea/src staged in LDS,
// read back via uniform-address (broadcast) ds_read. 8 gathers in flight (ping-pong).
// Logit reduce: 10-shuffle fold of 8 edges at once + 8-float LDS bounce.
__global__ __launch_bounds__(256, 4) void k_node(
    const float* __restrict__ xl, const float* __restrict__ xr,
    const float* __restrict__ edge_attr, const float* __restrict__ We,
    const float* __restrict__ att, const float* __restrict__ bias_conv,
    const int* __restrict__ deg, const int2* __restrict__ list,
    float* __restrict__ hN, int N)
{
    __shared__ float ea_s[NPB][CAP][EA_STRIDE]; // 20 KB
    __shared__ int   srcs_s[NPB][CAP];          //  1 KB
    __shared__ float T_s[NPB][8];               // 128 B

    const int tid  = threadIdx.x;
    const int lane = tid & 63;
    const int w    = tid >> 6;
    const int n    = blockIdx.x * NPB + w;
    if (n >= N) return;   // no barriers anywhere in this kernel

    // per-lane constants
    const float2 at2 = *reinterpret_cast<const float2*>(&att[2 * lane]);
    const float2 xr2 = *reinterpret_cast<const float2*>(&xr[(size_t)n * HDIM + 2 * lane]);
    float2 Wreg[DE];
    #pragma unroll
    for (int k = 0; k < DE; ++k)
        Wreg[k] = *reinterpret_cast<const float2*>(&We[k * HDIM + 2 * lane]);

    const int dfull  = deg[n];
    const int dcap   = dfull < (CAP - 1) ? dfull : (CAP - 1);
    const int cnt    = dcap + 1;           // incl. self loop at slot dcap
    const int nb     = (cnt + 7) >> 3;
    const int padcnt = nb * 8;

    // ---- stage: lane j handles edge j ----
    if (lane < dcap) {
        int2 se = list[(size_t)n * CAP + lane];
        srcs_s[w][lane] = se.x;
        const float4* ep = reinterpret_cast<const float4*>(&edge_attr[(size_t)se.y * DE]);
        float4 v0 = ep[0], v1 = ep[1], v2 = ep[2], v3 = ep[3];
        float* row = &ea_s[w][lane][0];
        *reinterpret_cast<float4*>(row + 0)  = v0;
        *reinterpret_cast<float4*>(row + 4)  = v1;
        *reinterpret_cast<float4*>(row + 8)  = v2;
        *reinterpret_cast<float4*>(row + 12) = v3;
    } else if (lane < padcnt) {
        srcs_s[w][lane] = n;               // self loop slot + padding: valid row
    }
    asm volatile("s_waitcnt lgkmcnt(0)" ::: "memory");

    // self-loop attr = column means of incoming ea (LDS column sums, no bpermute storm)
    {
        const int k = lane & 15, q = lane >> 4;
        float s = 0.f;
        for (int j = q; j < dcap; j += 4) s += ea_s[w][j][k];
        s += __shfl_xor(s, 16);
        s += __shfl_xor(s, 32);
        if (q == 0) ea_s[w][dcap][k] = s / (float)(dfull > 1 ? dfull : 1);
    }
    asm volatile("s_waitcnt lgkmcnt(0)" ::: "memory");

    // ---- online softmax state ----
    float m = -1e30f, d = 0.f, o0 = 0.f, o1 = 0.f;

    float2 A[8], B[8];
    int sA[8], sB[8];

    auto loadS = [&](int* s, int b) {
        const int4* p = reinterpret_cast<const int4*>(&srcs_s[w][b * 8]);
        int4 u0 = p[0], u1 = p[1];
        s[0] = u0.x; s[1] = u0.y; s[2] = u0.z; s[3] = u0.w;
        s[4] = u1.x; s[5] = u1.y; s[6] = u1.z; s[7] = u1.w;
    };
    auto issue = [&](float2* R, const int* s) {
        #pragma unroll
        for (int jj = 0; jj < 8; ++jj)
            R[jj] = *reinterpret_cast<const float2*>(&xl[(size_t)s[jj] * HDIM + 2 * lane]);
    };
    auto compute = [&](float2* R, int b) {
        const int j0 = b * 8;
        float p[8];
        #pragma unroll
        for (int jj = 0; jj < 8; ++jj) {
            const float* ear = &ea_s[w][j0 + jj][0];
            float4 e0 = *reinterpret_cast<const float4*>(ear + 0);
            float4 e1 = *reinterpret_cast<const float4*>(ear + 4);
            float4 e2 = *reinterpret_cast<const float4*>(ear + 8);
            float4 e3 = *reinterpret_cast<const float4*>(ear + 12);
            float s0 = xr2.x, s1 = xr2.y;
            s0 = fmaf(e0.x, Wreg[0].x,  s0); s1 = fmaf(e0.x, Wreg[0].y,  s1);
            s0 = fmaf(e0.y, Wreg[1].x,  s0); s1 = fmaf(e0.y, Wreg[1].y,  s1);
            s0 = fmaf(e0.z, Wreg[2].x,  s0); s1 = fmaf(e0.z, Wreg[2].y,  s1);
            s0 = fmaf(e0.w, Wreg[3].x,  s0); s1 = fmaf(e0.w, Wreg[3].y,  s1);
            s0 = fmaf(e1.x, Wreg[4].x,  s0); s1 = fmaf(e1.x, Wreg[4].y,  s1);
            s0 = fmaf(e1.y, Wreg[5].x,  s0); s1 = fmaf(e1.y, Wreg[5].y,  s1);
            s0 = fmaf(e1.z, Wreg[6].x,  s0); s1 = fmaf(e1.z, Wreg[6].y,  s1);
            s0 = fmaf(e1.w, Wreg[7].x,  s0); s1 = fmaf(e1.w, Wreg[7].y,  s1);
            s0 = fmaf(e2.x, Wreg[8].x,  s0); s1 = fmaf(e2.x, Wreg[8].y,  s1);
            s0 = fmaf(e2.y, Wreg[9].x,  s0); s1 = fmaf(e2.y, Wreg[9].y,  s1);
            s0 = fmaf(e2.z, Wreg[10].x, s0); s1 = fmaf(e2.z, Wreg[10].y, s1);
            s0 = fmaf(e2.w, Wreg[11].x, s0); s1 = fmaf(e2.w, Wreg[11].y, s1);
            s0 = fmaf(e3.x, Wreg[12].x, s0); s1 = fmaf(e3.x, Wreg[12].y, s1);
            s0 = fmaf(e3.y, Wreg[13].x, s0); s1 = fmaf(e3.y, Wreg[13].y, s1);
            s0 = fmaf(e3.z, Wreg[14].x, s0); s1 = fmaf(e3.z, Wreg[14].y, s1);
            s0 = fmaf(e3.w, Wreg[15].x, s0); s1 = fmaf(e3.w, Wreg[15].y, s1);
            s0 += R[jj].x;
            s1 += R[jj].y;
            s0 = s0 > 0.f ? s0 : NEG_SLOPE * s0;
            s1 = s1 > 0.f ? s1 : NEG_SLOPE * s1;
            p[jj] = fmaf(s0, at2.x, s1 * at2.y);
        }
        // fold: 8 edges x 64 lanes -> 8 totals, in 10 shuffles
        {   // o=1: 8 -> 4
            float sd0 = (lane & 1) ? p[0] : p[4];
            float sd1 = (lane & 1) ? p[1] : p[5];
            float sd2 = (lane & 1) ? p[2] : p[6];
            float sd3 = (lane & 1) ? p[3] : p[7];
            float r0 = __shfl_xor(sd0, 1), r1 = __shfl_xor(sd1, 1);
            float r2 = __shfl_xor(sd2, 1), r3 = __shfl_xor(sd3, 1);
            p[0] = ((lane & 1) ? p[4] : p[0]) + r0;
            p[1] = ((lane & 1) ? p[5] : p[1]) + r1;
            p[2] = ((lane & 1) ? p[6] : p[2]) + r2;
            p[3] = ((lane & 1) ? p[7] : p[3]) + r3;
        }
        {   // o=2: 4 -> 2
            float sd0 = (lane & 2) ? p[0] : p[2];
            float sd1 = (lane & 2) ? p[1] : p[3];
            float r0 = __shfl_xor(sd0, 2), r1 = __shfl_xor(sd1, 2);
            p[0] = ((lane & 2) ? p[2] : p[0]) + r0;
            p[1] = ((lane & 2) ? p[3] : p[1]) + r1;
        }
        {   // o=4: 2 -> 1
            float sd = (lane & 4) ? p[0] : p[1];
            float r = __shfl_xor(sd, 4);
            p[0] = ((lane & 4) ? p[1] : p[0]) + r;
        }
        float t = p[0];
        t += __shfl_xor(t, 8);
        t += __shfl_xor(t, 16);
        t += __shfl_xor(t, 32);
        // lane l<8 holds T[bitrev3(l)] -> ordered bounce through LDS
        if (lane < 8) {
            int e = ((lane & 1) << 2) | (lane & 2) | ((lane >> 2) & 1);
            T_s[w][e] = t;
        }
        asm volatile("s_waitcnt lgkmcnt(0)" ::: "memory");
        float4 t0 = *reinterpret_cast<const float4*>(&T_s[w][0]);
        float4 t1 = *reinterpret_cast<const float4*>(&T_s[w][4]);
        float tt[8] = {t0.x, t0.y, t0.z, t0.w, t1.x, t1.y, t1.z, t1.w};

        const int bk = cnt - j0;               // valid edges this batch (>=1)
        float mx = m;
        #pragma unroll
        for (int jj = 0; jj < 8; ++jj) {
            if (jj >= bk) tt[jj] = -1e30f;
            mx = fmaxf(mx, tt[jj]);
        }
        const float sc = __expf(m - mx);
        float pj[8], psum = 0.f;
        #pragma unroll
        for (int jj = 0; jj < 8; ++jj) { pj[jj] = __expf(tt[jj] - mx); psum += pj[jj]; }
        d = fmaf(d, sc, psum);
        float acc0 = 0.f, acc1 = 0.f;
        #pragma unroll
        for (int jj = 0; jj < 8; ++jj) {
            acc0 = fmaf(pj[jj], R[jj].x, acc0);
            acc1 = fmaf(pj[jj], R[jj].y, acc1);
        }
        o0 = fmaf(o0, sc, acc0);
        o1 = fmaf(o1, sc, acc1);
        m = mx;
    };

    loadS(sA, 0); issue(A, sA);
    for (int b = 0; b < nb; ++b) {
        const bool odd = (b & 1) != 0;
        if (b + 1 < nb) {
            if (odd) { loadS(sA, b + 1); issue(A, sA); }
            else     { loadS(sB, b + 1); issue(B, sB); }
        }
        if (odd) compute(B, b); else compute(A, b);
    }

    const float inv = 1.f / d;
    const float2 bc2 = *reinterpret_cast<const float2*>(&bias_conv[2 * lane]);
    float2 res;
    res.x = fmaxf(fmaf(o0, inv, bc2.x), 0.f);
    res.y = fmaxf(fmaf(o1, inv, bc2.y), 0.f);
    *reinterpret_cast<float2*>(&hN[(size_t)n * HDIM + 2 * lane]) = res;
}

// ---------------- pooled sums per graph (batch is sorted) ----------------
__global__ __launch_bounds__(128) void k_pool(
    const float* __restrict__ hN, const int* __restrict__ batch,
    float* __restrict__ pool, int* __restrict__ cnt, int N)
{
    const int t  = threadIdx.x;          // dim
    const int n0 = blockIdx.x * 256;
    if (n0 >= N) return;
    const int n1 = (n0 + 256 < N) ? (n0 + 256) : N;
    int curg = batch[n0];
    float acc = 0.f;
    int c = 0;
    for (int nn = n0; nn < n1; ++nn) {
        int g = batch[nn];
        if (g != curg) {
            atomicAdd(&pool[curg * HDIM + t], acc);
            if (t == 0) atomicAdd(&cnt[curg], c);
            acc = 0.f; c = 0; curg = g;
        }
        acc += hN[(size_t)nn * HDIM + t];
        ++c;
    }
    atomicAdd(&pool[curg * HDIM + t], acc);
    if (t == 0) atomicAdd(&cnt[curg], c);
}

// ---------------- final classifier ----------------
__global__ void k_final(const float* __restrict__ pool, const int* __restrict__ cnt,
                        const float* __restrict__ Wc, const float* __restrict__ bc,
                        float* __restrict__ out)
{
    int t = threadIdx.x;
    if (t < GG * 2) {
        int g = t >> 1, c = t & 1;
        float inv = 1.f / (float)(cnt[g] > 1 ? cnt[g] : 1);
        float s = 0.f;
        #pragma unroll 16
        for (int h = 0; h < HDIM; ++h) s += pool[g * HDIM + h] * Wc[h * 2 + c];
        out[t] = s * inv + bc[c];
    }
}

extern "C" void kernel_launch(void* const* d_in, const int* in_sizes, int n_in,
                              void* d_out, int out_size, void* d_ws, size_t ws_size,
                              hipStream_t stream) {
    const float* x         = (const float*)d_in[0];
    const int*   ei        = (const int*)  d_in[1];
    const float* edge_attr = (const float*)d_in[2];
    const int*   batch     = (const int*)  d_in[3];
    const float* Wl        = (const float*)d_in[4];
    const float* bl        = (const float*)d_in[5];
    const float* Wr        = (const float*)d_in[6];
    const float* br        = (const float*)d_in[7];
    const float* We        = (const float*)d_in[8];
    const float* att       = (const float*)d_in[9];
    const float* bias_conv = (const float*)d_in[10];
    const float* Wc        = (const float*)d_in[11];
    const float* bc        = (const float*)d_in[12];
    float* out = (float*)d_out;

    const int N = in_sizes[0] / FDIM;
    const int E = in_sizes[1] / 2;
    const int* srcp = ei;
    const int* dstp = ei + E;

    // workspace carve-up (256B aligned)
    char* ws = (char*)d_ws;
    size_t off = 0;
    auto alloc = [&](size_t bytes) { char* p = ws + off; off = (off + bytes + 255) & ~(size_t)255; return p; };
    int*   cursor = (int*)  alloc((size_t)N * 4);          // doubles as degree
    int2*  list   = (int2*) alloc((size_t)N * CAP * 8);
    float* xl     = (float*)alloc((size_t)N * HDIM * 4);
    float* xr     = (float*)alloc((size_t)N * HDIM * 4);
    float* hN     = (float*)alloc((size_t)N * HDIM * 4);
    float* pool   = (float*)alloc((size_t)GG * HDIM * 4);
    int*   cnt    = (int*)  alloc((size_t)GG * 4);

    hipMemsetAsync(cursor, 0, (size_t)N * 4, stream);
    hipMemsetAsync(pool,   0, (size_t)GG * HDIM * 4, stream);
    hipMemsetAsync(cnt,    0, (size_t)GG * 4, stream);

    k_scatter<<<(E + 255) / 256, 256, 0, stream>>>(srcp, dstp, cursor, list, E);
    k_gemm   <<<dim3((N + 127) / 128, 4), 256, 0, stream>>>(x, Wl, bl, Wr, br, xl, xr, N);
    k_node   <<<(N + NPB - 1) / NPB, 256, 0, stream>>>(xl, xr, edge_attr, We, att, bias_conv,
                                                       cursor, list, hN, N);
    k_pool   <<<(N + 255) / 256, 128, 0, stream>>>(hN, batch, pool, cnt, N);
    k_final  <<<1, 64, 0, stream>>>(pool, cnt, Wc, bc, out);
}

// Round 5
// 396.130 us; speedup vs baseline: 1.9876x; 1.0806x over previous
//
#include <hip/hip_runtime.h>

// Problem constants (fixed by the reference)
#define FDIM 128   // input features
#define HDIM 128   // hidden
#define DE   16    // edge attr dim
#define GG   32    // graphs
#define CAP  64    // max edges per node incl. self loop (deg capped at 63)
#define NPB  4     // nodes per block (one wave per node)
#define EA_STRIDE 20  // padded LDS row stride (floats); [0..15]=ea, [16]=src bits, [17]=T slot
#define NEG_SLOPE 0.2f

// ---------------- scatter edges into padded CSR lists (cursor == degree) ----------------
__global__ void k_scatter(const int* __restrict__ src, const int* __restrict__ dst,
                          int* __restrict__ cursor, int2* __restrict__ list, int E) {
    int i = blockIdx.x * blockDim.x + threadIdx.x;
    if (i < E) {
        int d = dst[i];
        int p = atomicAdd(&cursor[d], 1);
        if (p < CAP - 1) list[d * CAP + p] = make_int2(src[i], i);
    }
}

// ---------------- single-pass dual GEMM: [xl|xr] = x @ [Wl|Wr] + [bl|br] ----------------
// grid ceil(M/64), block 256. 64 rows x 256 cols (Wl's 128 ++ Wr's 128) per block;
// x staged ONCE. Thread (tx=tid&31, ty=tid>>5): rows ty*8..+7, cols {tx*4 of Wl, tx*4 of Wr}.
// Block 0 additionally zeroes pool/cnt (needed before k_pool, saves 2 memset dispatches).
__global__ __launch_bounds__(256) void k_gemm(
    const float* __restrict__ x,
    const float* __restrict__ Wl, const float* __restrict__ bl,
    const float* __restrict__ Wr, const float* __restrict__ br,
    float* __restrict__ xl, float* __restrict__ xr, int M,
    float* __restrict__ pool, int* __restrict__ cnt)
{
    __shared__ float As[32][65];    // [k][m], +1 pad: conflict-free transposed stores
    __shared__ float Bs[32][260];   // [k][col], cols 0-127 = Wl, 128-255 = Wr; +4 pad

    const int tid = threadIdx.x;
    if (blockIdx.x == 0) {
        #pragma unroll
        for (int i = tid; i < GG * HDIM; i += 256) pool[i] = 0.f;
        if (tid < GG) cnt[tid] = 0;
    }
    const int r0 = blockIdx.x * 64;
    const int tx = tid & 31, ty = tid >> 5;
    float acc[8][8] = {};   // [row][0-3: Wl cols, 4-7: Wr cols]

    for (int kc = 0; kc < FDIM; kc += 32) {
        // stage A: 64 rows x 32 k (transposed) -> 512 float4, 2/thread
        #pragma unroll
        for (int vv = 0; vv < 2; ++vv) {
            int v = tid + vv * 256;
            int mrow = v >> 3, kq = v & 7;
            int r = r0 + mrow; r = (r < M) ? r : (M - 1);
            float4 xv = *reinterpret_cast<const float4*>(&x[(size_t)r * FDIM + kc + kq * 4]);
            As[kq * 4 + 0][mrow] = xv.x;
            As[kq * 4 + 1][mrow] = xv.y;
            As[kq * 4 + 2][mrow] = xv.z;
            As[kq * 4 + 3][mrow] = xv.w;
        }
        // stage B: 32 k x 256 cols -> 2048 float4, 8/thread
        #pragma unroll
        for (int vv = 0; vv < 8; ++vv) {
            int v = tid + vv * 256;
            int k = v >> 6, cq = v & 63;
            const float* Wp = (cq < 32) ? &Wl[(size_t)(kc + k) * HDIM + cq * 4]
                                        : &Wr[(size_t)(kc + k) * HDIM + (cq - 32) * 4];
            *reinterpret_cast<float4*>(&Bs[k][cq * 4]) = *reinterpret_cast<const float4*>(Wp);
        }
        __syncthreads();
        #pragma unroll
        for (int k = 0; k < 32; ++k) {
            float4 b0 = *reinterpret_cast<const float4*>(&Bs[k][tx * 4]);
            float4 b1 = *reinterpret_cast<const float4*>(&Bs[k][128 + tx * 4]);
            float4 a0 = *reinterpret_cast<const float4*>(&As[k][ty * 8]);
            float4 a1 = *reinterpret_cast<const float4*>(&As[k][ty * 8 + 4]);
            float a8[8] = {a0.x, a0.y, a0.z, a0.w, a1.x, a1.y, a1.z, a1.w};
            #pragma unroll
            for (int i = 0; i < 8; ++i) {
                acc[i][0] = fmaf(a8[i], b0.x, acc[i][0]);
                acc[i][1] = fmaf(a8[i], b0.y, acc[i][1]);
                acc[i][2] = fmaf(a8[i], b0.z, acc[i][2]);
                acc[i][3] = fmaf(a8[i], b0.w, acc[i][3]);
                acc[i][4] = fmaf(a8[i], b1.x, acc[i][4]);
                acc[i][5] = fmaf(a8[i], b1.y, acc[i][5]);
                acc[i][6] = fmaf(a8[i], b1.z, acc[i][6]);
                acc[i][7] = fmaf(a8[i], b1.w, acc[i][7]);
            }
        }
        __syncthreads();
    }
    float4 bvl = *reinterpret_cast<const float4*>(&bl[tx * 4]);
    float4 bvr = *reinterpret_cast<const float4*>(&br[tx * 4]);
    #pragma unroll
    for (int i = 0; i < 8; ++i) {
        int r = r0 + ty * 8 + i;
        if (r < M) {
            float4 ol, orr;
            ol.x  = acc[i][0] + bvl.x; ol.y  = acc[i][1] + bvl.y;
            ol.z  = acc[i][2] + bvl.z; ol.w  = acc[i][3] + bvl.w;
            orr.x = acc[i][4] + bvr.x; orr.y = acc[i][5] + bvr.y;
            orr.z = acc[i][6] + bvr.z; orr.w = acc[i][7] + bvr.w;
            *reinterpret_cast<float4*>(&xl[(size_t)r * HDIM + tx * 4]) = ol;
            *reinterpret_cast<float4*>(&xr[(size_t)r * HDIM + tx * 4]) = orr;
        }
    }
}

// ---------------- fused per-node kernel: ONE WAVE PER NODE, 8-EDGE BATCHES ----------------
// LDS = exactly 20480 B (8 blocks/CU). Row j of ea_s: [0..15]=edge_attr, [16]=src bits,
// [17]=logit-bounce slot (rows 0..7). Gathers double-buffered 8-deep; batch-0 gathers
// issued before the self-loop-mean to hide latency.
__global__ __launch_bounds__(256, 4) void k_node(
    const float* __restrict__ xl, const float* __restrict__ xr,
    const float* __restrict__ edge_attr, const float* __restrict__ We,
    const float* __restrict__ att, const float* __restrict__ bias_conv,
    const int* __restrict__ deg, const int2* __restrict__ list,
    float* __restrict__ hN, int N)
{
    __shared__ float ea_s[NPB][CAP][EA_STRIDE]; // 20480 B exactly

    const int tid  = threadIdx.x;
    const int lane = tid & 63;
    const int w    = tid >> 6;
    const int n    = blockIdx.x * NPB + w;
    if (n >= N) return;   // no barriers anywhere in this kernel

    // per-lane constants
    const float2 at2 = *reinterpret_cast<const float2*>(&att[2 * lane]);
    const float2 xr2 = *reinterpret_cast<const float2*>(&xr[(size_t)n * HDIM + 2 * lane]);
    float2 Wreg[DE];
    #pragma unroll
    for (int k = 0; k < DE; ++k)
        Wreg[k] = *reinterpret_cast<const float2*>(&We[k * HDIM + 2 * lane]);

    const int dfull  = deg[n];
    const int dcap   = dfull < (CAP - 1) ? dfull : (CAP - 1);
    const int cnt    = dcap + 1;           // incl. self loop at slot dcap
    const int nb     = (cnt + 7) >> 3;
    const int padcnt = nb * 8;

    // ---- stage: lane j handles edge j ----
    if (lane < dcap) {
        int2 se = list[(size_t)n * CAP + lane];
        const float4* ep = reinterpret_cast<const float4*>(&edge_attr[(size_t)se.y * DE]);
        float4 v0 = ep[0], v1 = ep[1], v2 = ep[2], v3 = ep[3];
        float* row = &ea_s[w][lane][0];
        *reinterpret_cast<float4*>(row + 0)  = v0;
        *reinterpret_cast<float4*>(row + 4)  = v1;
        *reinterpret_cast<float4*>(row + 8)  = v2;
        *reinterpret_cast<float4*>(row + 12) = v3;
        row[16] = __int_as_float(se.x);
    } else if (lane < padcnt) {
        ea_s[w][lane][16] = __int_as_float(n);   // self loop + padding: valid src
    }
    asm volatile("s_waitcnt lgkmcnt(0)" ::: "memory");

    float2 A[8], B[8];
    int sA[8], sB[8];

    auto loadS = [&](int* s, int b) {
        #pragma unroll
        for (int jj = 0; jj < 8; ++jj)
            s[jj] = __float_as_int(ea_s[w][b * 8 + jj][16]);   // uniform-addr broadcast
    };
    auto issue = [&](float2* R, const int* s) {
        #pragma unroll
        for (int jj = 0; jj < 8; ++jj)
            R[jj] = *reinterpret_cast<const float2*>(&xl[(size_t)s[jj] * HDIM + 2 * lane]);
    };

    // kick off batch-0 gathers before computing the self-loop mean (hide latency)
    loadS(sA, 0);
    issue(A, sA);

    // self-loop attr = column means of incoming ea
    {
        const int k = lane & 15, q = lane >> 4;
        float s = 0.f;
        for (int j = q; j < dcap; j += 4) s += ea_s[w][j][k];
        s += __shfl_xor(s, 16);
        s += __shfl_xor(s, 32);
        if (q == 0) ea_s[w][dcap][k] = s / (float)(dfull > 1 ? dfull : 1);
    }
    asm volatile("s_waitcnt lgkmcnt(0)" ::: "memory");

    // ---- online softmax state ----
    float m = -1e30f, d = 0.f, o0 = 0.f, o1 = 0.f;

    auto compute = [&](float2* R, int b) {
        const int j0 = b * 8;
        float p[8];
        #pragma unroll
        for (int jj = 0; jj < 8; ++jj) {
            const float* ear = &ea_s[w][j0 + jj][0];
            float4 e0 = *reinterpret_cast<const float4*>(ear + 0);
            float4 e1 = *reinterpret_cast<const float4*>(ear + 4);
            float4 e2 = *reinterpret_cast<const float4*>(ear + 8);
            float4 e3 = *reinterpret_cast<const float4*>(ear + 12);
            float s0 = xr2.x, s1 = xr2.y;
            s0 = fmaf(e0.x, Wreg[0].x,  s0); s1 = fmaf(e0.x, Wreg[0].y,  s1);
            s0 = fmaf(e0.y, Wreg[1].x,  s0); s1 = fmaf(e0.y, Wreg[1].y,  s1);
            s0 = fmaf(e0.z, Wreg[2].x,  s0); s1 = fmaf(e0.z, Wreg[2].y,  s1);
            s0 = fmaf(e0.w, Wreg[3].x,  s0); s1 = fmaf(e0.w, Wreg[3].y,  s1);
            s0 = fmaf(e1.x, Wreg[4].x,  s0); s1 = fmaf(e1.x, Wreg[4].y,  s1);
            s0 = fmaf(e1.y, Wreg[5].x,  s0); s1 = fmaf(e1.y, Wreg[5].y,  s1);
            s0 = fmaf(e1.z, Wreg[6].x,  s0); s1 = fmaf(e1.z, Wreg[6].y,  s1);
            s0 = fmaf(e1.w, Wreg[7].x,  s0); s1 = fmaf(e1.w, Wreg[7].y,  s1);
            s0 = fmaf(e2.x, Wreg[8].x,  s0); s1 = fmaf(e2.x, Wreg[8].y,  s1);
            s0 = fmaf(e2.y, Wreg[9].x,  s0); s1 = fmaf(e2.y, Wreg[9].y,  s1);
            s0 = fmaf(e2.z, Wreg[10].x, s0); s1 = fmaf(e2.z, Wreg[10].y, s1);
            s0 = fmaf(e2.w, Wreg[11].x, s0); s1 = fmaf(e2.w, Wreg[11].y, s1);
            s0 = fmaf(e3.x, Wreg[12].x, s0); s1 = fmaf(e3.x, Wreg[12].y, s1);
            s0 = fmaf(e3.y, Wreg[13].x, s0); s1 = fmaf(e3.y, Wreg[13].y, s1);
            s0 = fmaf(e3.z, Wreg[14].x, s0); s1 = fmaf(e3.z, Wreg[14].y, s1);
            s0 = fmaf(e3.w, Wreg[15].x, s0); s1 = fmaf(e3.w, Wreg[15].y, s1);
            s0 += R[jj].x;
            s1 += R[jj].y;
            s0 = s0 > 0.f ? s0 : NEG_SLOPE * s0;
            s1 = s1 > 0.f ? s1 : NEG_SLOPE * s1;
            p[jj] = fmaf(s0, at2.x, s1 * at2.y);
        }
        // fold: 8 edges x 64 lanes -> 8 totals, in 10 shuffles
        {   // o=1: 8 -> 4
            float sd0 = (lane & 1) ? p[0] : p[4];
            float sd1 = (lane & 1) ? p[1] : p[5];
            float sd2 = (lane & 1) ? p[2] : p[6];
            float sd3 = (lane & 1) ? p[3] : p[7];
            float r0 = __shfl_xor(sd0, 1), r1 = __shfl_xor(sd1, 1);
            float r2 = __shfl_xor(sd2, 1), r3 = __shfl_xor(sd3, 1);
            p[0] = ((lane & 1) ? p[4] : p[0]) + r0;
            p[1] = ((lane & 1) ? p[5] : p[1]) + r1;
            p[2] = ((lane & 1) ? p[6] : p[2]) + r2;
            p[3] = ((lane & 1) ? p[7] : p[3]) + r3;
        }
        {   // o=2: 4 -> 2
            float sd0 = (lane & 2) ? p[0] : p[2];
            float sd1 = (lane & 2) ? p[1] : p[3];
            float r0 = __shfl_xor(sd0, 2), r1 = __shfl_xor(sd1, 2);
            p[0] = ((lane & 2) ? p[2] : p[0]) + r0;
            p[1] = ((lane & 2) ? p[3] : p[1]) + r1;
        }
        {   // o=4: 2 -> 1
            float sd = (lane & 4) ? p[0] : p[1];
            float r = __shfl_xor(sd, 4);
            p[0] = ((lane & 4) ? p[1] : p[0]) + r;
        }
        float t = p[0];
        t += __shfl_xor(t, 8);
        t += __shfl_xor(t, 16);
        t += __shfl_xor(t, 32);
        // lane l<8 holds T[bitrev3(l)] -> ordered bounce through LDS slot [e][17]
        if (lane < 8) {
            int e = ((lane & 1) << 2) | (lane & 2) | ((lane >> 2) & 1);
            ea_s[w][e][17] = t;
        }
        asm volatile("s_waitcnt lgkmcnt(0)" ::: "memory");
        float tt[8];
        #pragma unroll
        for (int jj = 0; jj < 8; ++jj) tt[jj] = ea_s[w][jj][17];   // uniform broadcast

        const int bk = cnt - j0;               // valid edges this batch (>=1)
        float mx = m;
        #pragma unroll
        for (int jj = 0; jj < 8; ++jj) {
            if (jj >= bk) tt[jj] = -1e30f;
            mx = fmaxf(mx, tt[jj]);
        }
        const float sc = __expf(m - mx);
        float pj[8], psum = 0.f;
        #pragma unroll
        for (int jj = 0; jj < 8; ++jj) { pj[jj] = __expf(tt[jj] - mx); psum += pj[jj]; }
        d = fmaf(d, sc, psum);
        float acc0 = 0.f, acc1 = 0.f;
        #pragma unroll
        for (int jj = 0; jj < 8; ++jj) {
            acc0 = fmaf(pj[jj], R[jj].x, acc0);
            acc1 = fmaf(pj[jj], R[jj].y, acc1);
        }
        o0 = fmaf(o0, sc, acc0);
        o1 = fmaf(o1, sc, acc1);
        m = mx;
    };

    for (int b = 0; b < nb; ++b) {
        const bool odd = (b & 1) != 0;
        if (b + 1 < nb) {
            if (odd) { loadS(sA, b + 1); issue(A, sA); }
            else     { loadS(sB, b + 1); issue(B, sB); }
        }
        if (odd) compute(B, b); else compute(A, b);
    }

    const float inv = 1.f / d;
    const float2 bc2 = *reinterpret_cast<const float2*>(&bias_conv[2 * lane]);
    float2 res;
    res.x = fmaxf(fmaf(o0, inv, bc2.x), 0.f);
    res.y = fmaxf(fmaf(o1, inv, bc2.y), 0.f);
    *reinterpret_cast<float2*>(&hN[(size_t)n * HDIM + 2 * lane]) = res;
}

// ---------------- pooled sums per graph (batch is sorted; 64-node chunks) ----------------
__global__ __launch_bounds__(128) void k_pool(
    const float* __restrict__ hN, const int* __restrict__ batch,
    float* __restrict__ pool, int* __restrict__ cnt, int N)
{
    const int t  = threadIdx.x;          // dim
    const int n0 = blockIdx.x * 64;
    if (n0 >= N) return;
    const int n1 = (n0 + 64 < N) ? (n0 + 64) : N;
    int curg = batch[n0];
    float acc = 0.f;
    int c = 0;
    for (int nn = n0; nn < n1; ++nn) {
        int g = batch[nn];
        if (g != curg) {
            atomicAdd(&pool[curg * HDIM + t], acc);
            if (t == 0) atomicAdd(&cnt[curg], c);
            acc = 0.f; c = 0; curg = g;
        }
        acc += hN[(size_t)nn * HDIM + t];
        ++c;
    }
    atomicAdd(&pool[curg * HDIM + t], acc);
    if (t == 0) atomicAdd(&cnt[curg], c);
}

// ---------------- final classifier ----------------
__global__ void k_final(const float* __restrict__ pool, const int* __restrict__ cnt,
                        const float* __restrict__ Wc, const float* __restrict__ bc,
                        float* __restrict__ out)
{
    int t = threadIdx.x;
    if (t < GG * 2) {
        int g = t >> 1, c = t & 1;
        float inv = 1.f / (float)(cnt[g] > 1 ? cnt[g] : 1);
        float s = 0.f;
        #pragma unroll 16
        for (int h = 0; h < HDIM; ++h) s += pool[g * HDIM + h] * Wc[h * 2 + c];
        out[t] = s * inv + bc[c];
    }
}

extern "C" void kernel_launch(void* const* d_in, const int* in_sizes, int n_in,
                              void* d_out, int out_size, void* d_ws, size_t ws_size,
                              hipStream_t stream) {
    const float* x         = (const float*)d_in[0];
    const int*   ei        = (const int*)  d_in[1];
    const float* edge_attr = (const float*)d_in[2];
    const int*   batch     = (const int*)  d_in[3];
    const float* Wl        = (const float*)d_in[4];
    const float* bl        = (const float*)d_in[5];
    const float* Wr        = (const float*)d_in[6];
    const float* br        = (const float*)d_in[7];
    const float* We        = (const float*)d_in[8];
    const float* att       = (const float*)d_in[9];
    const float* bias_conv = (const float*)d_in[10];
    const float* Wc        = (const float*)d_in[11];
    const float* bc        = (const float*)d_in[12];
    float* out = (float*)d_out;

    const int N = in_sizes[0] / FDIM;
    const int E = in_sizes[1] / 2;
    const int* srcp = ei;
    const int* dstp = ei + E;

    // workspace carve-up (256B aligned)
    char* ws = (char*)d_ws;
    size_t off = 0;
    auto alloc = [&](size_t bytes) { char* p = ws + off; off = (off + bytes + 255) & ~(size_t)255; return p; };
    int*   cursor = (int*)  alloc((size_t)N * 4);          // doubles as degree
    int2*  list   = (int2*) alloc((size_t)N * CAP * 8);
    float* xl     = (float*)alloc((size_t)N * HDIM * 4);
    float* xr     = (float*)alloc((size_t)N * HDIM * 4);
    float* hN     = (float*)alloc((size_t)N * HDIM * 4);
    float* pool   = (float*)alloc((size_t)GG * HDIM * 4);
    int*   cnt    = (int*)  alloc((size_t)GG * 4);

    hipMemsetAsync(cursor, 0, (size_t)N * 4, stream);

    k_scatter<<<(E + 255) / 256, 256, 0, stream>>>(srcp, dstp, cursor, list, E);
    k_gemm   <<<(N + 63) / 64, 256, 0, stream>>>(x, Wl, bl, Wr, br, xl, xr, N, pool, cnt);
    k_node   <<<(N + NPB - 1) / NPB, 256, 0, stream>>>(xl, xr, edge_attr, We, att, bias_conv,
                                                       cursor, list, hN, N);
    k_pool   <<<(N + 63) / 64, 128, 0, stream>>>(hN, batch, pool, cnt, N);
    k_final  <<<1, 64, 0, stream>>>(pool, cnt, Wc, bc, out);
}